// Round 3
// baseline (254.832 us; speedup 1.0000x reference)
//
#include <hip/hip_runtime.h>

#define B_SZ  128
#define MCHK  288
#define NVAR  576
#define KINFO 288
#define NITER 5
#define MH    144          // check rows per block (2 blocks per batch element)
#define ECAP  2048         // edge capacity per half (mean 1659, sd ~40 -> 9.7 sigma)
#define TPB   1024

// ---------------------------------------------------------------------------
// Single fused kernel. Grid = 256 blocks: block (2b+g) owns rows [g*144,(g+1)*144)
// of batch element b. Edge extraction from H (coalesced float4, ballot compact,
// LDS-atomic slot allocation), then 5 BP iterations with one device-scope
// grid barrier per iteration to exchange per-variable partial sums.
// All 256 blocks are co-resident (16 waves, <=128 VGPR, ~43 KB LDS) so the
// spin barrier cannot deadlock.
// ---------------------------------------------------------------------------
__global__ __launch_bounds__(TPB) void decode(
    const float* __restrict__ inp,   const float* __restrict__ H,
    const float* __restrict__ sigma2,const float* __restrict__ ipond,
    const float* __restrict__ opond, const float* __restrict__ skipp,
    const float* __restrict__ wcv,   const float* __restrict__ gatel,
    float* __restrict__ Sg, int* __restrict__ bar, float* __restrict__ out)
{
    __shared__ float Mld[ECAP];          // per-edge message
    __shared__ float tld[ECAP];          // per-edge tanh
    __shared__ float wld[ECAP];          // per-edge w_cv
    __shared__ unsigned int ev[ECAP];    // per-edge (local_row<<16)|var
    __shared__ float xln[NVAR];          // normalized LLRs
    __shared__ float xs[NVAR];           // pt*xln + S_total (next iteration's v2c base)
    __shared__ float Spart[NVAR];        // this block's partial message sum
    __shared__ float pooled[KINFO];
    __shared__ float Prow[MH];
    __shared__ int   rcnt[MH], roff[MH];
    __shared__ float red[16];
    __shared__ float scalS;
    __shared__ int   Ecnt;

    const int bid  = blockIdx.x;
    const int b    = bid >> 1;
    const int grp  = bid & 1;
    const int tid  = threadIdx.x;
    const int wid  = tid >> 6;
    const int lane = tid & 63;
    const int rlo  = grp * MH;

    const float sig  = sigma2[b];
    const float gate = 1.0f / (1.0f + __expf(-gatel[0]));
    const float gbar = 1.0f - gate;

    float ipl[NITER], opl[NITER];
    #pragma unroll
    for (int t = 0; t < NITER; ++t) { ipl[t] = ipond[t]; opl[t] = opond[t]; }

    // ---- llrs = -4*in/sigma2 ; mean|llr| normalization ----
    float l = 0.0f, al = 0.0f;
    if (tid < NVAR) { l = -4.0f * inp[(size_t)b * NVAR + tid] / sig; al = fabsf(l); }
    #pragma unroll
    for (int o = 32; o; o >>= 1) al += __shfl_down(al, o, 64);
    if (lane == 0) red[wid] = al;
    if (tid == 0) Ecnt = 0;
    __syncthreads();
    if (tid == 0) {
        float s = 0.0f;
        #pragma unroll
        for (int i = 0; i < 16; ++i) s += red[i];
        scalS = (float)NVAR / s;
    }
    __syncthreads();
    if (tid < NVAR) {
        float xv = l * scalS;
        xln[tid] = xv;
        xs[tid]  = ipl[0] * xv;          // S_total = 0 at iteration 0
    }
    if (tid < KINFO) pooled[tid] = 0.0f;

    // ---- edge extraction: wave w handles local rows w, w+16, ... ----
    {
        const float* Hb = H + ((size_t)b * MCHK + rlo) * NVAR;
        const unsigned long long lt = (1ull << lane) - 1ull;
        for (int i = 0; i < MH / 16; ++i) {
            int lr = wid + 16 * i;
            const float* hr = Hb + (size_t)lr * NVAR;
            const float4* h4 = (const float4*)hr;
            float4 a  = h4[lane];
            float4 b4 = h4[64 + lane];
            float  c  = hr[512 + lane];
            unsigned long long mk[9];
            mk[0]=__ballot(a.x!=0.f);  mk[1]=__ballot(a.y!=0.f);
            mk[2]=__ballot(a.z!=0.f);  mk[3]=__ballot(a.w!=0.f);
            mk[4]=__ballot(b4.x!=0.f); mk[5]=__ballot(b4.y!=0.f);
            mk[6]=__ballot(b4.z!=0.f); mk[7]=__ballot(b4.w!=0.f);
            mk[8]=__ballot(c!=0.f);
            int tot = 0;
            #pragma unroll
            for (int k = 0; k < 9; ++k) tot += __popcll(mk[k]);
            int o0 = 0;
            if (lane == 0) o0 = atomicAdd(&Ecnt, tot);
            o0 = __shfl(o0, 0, 64);
            int cc = (o0 >= ECAP) ? 0 : ((o0 + tot > ECAP) ? (ECAP - o0) : tot);
            if (lane == 0) { roff[lr] = o0; rcnt[lr] = cc; }
            const float* wrow = wcv + (size_t)(rlo + lr) * NVAR;
            int base = 0;
            #pragma unroll
            for (int k = 0; k < 9; ++k) {
                bool nz = (mk[k] >> lane) & 1ull;
                int col = (k < 4) ? (4 * lane + k)
                        : (k < 8) ? (256 + 4 * lane + (k - 4))
                                  : (512 + lane);
                if (nz) {
                    int p = base + __popcll(mk[k] & lt);
                    if (p < cc) {
                        int e = o0 + p;
                        ev[e]  = ((unsigned)lr << 16) | (unsigned)col;
                        wld[e] = wrow[col];
                        Mld[e] = 0.0f;
                    }
                }
                base += __popcll(mk[k]);
            }
        }
    }
    __syncthreads();
    const int E1 = (Ecnt > ECAP) ? ECAP : Ecnt;

    // ---- 5 BP iterations, one grid barrier each ----
    for (int t = 0; t < NITER; ++t) {
        const float pt = ipl[t], ot = opl[t];

        // pass 1: per-edge tanh(0.5*clip(xs[v]-M))
        for (int e = tid; e < E1; e += TPB) {
            int v   = (int)(ev[e] & 0xFFFFu);
            float V = xs[v] - Mld[e];
            V = fminf(15.0f, fmaxf(-15.0f, V));
            float ex = __expf(V);
            float te = (ex - 1.0f) * __builtin_amdgcn_rcpf(ex + 1.0f);
            float x  = 0.5f * V, x2 = x * x;
            float tp = x * fmaf(x2, fmaf(x2, fmaf(x2, -0.05396825f, 0.13333333f),
                                         -0.33333333f), 1.0f);
            tld[e] = (fabsf(V) < 0.5f) ? tp : te;
        }
        __syncthreads();

        // row products; zero partial S
        if (tid < MH) {
            int c = rcnt[tid], o = roff[tid];
            float P = 1.0f;
            for (int j = 0; j < c; ++j) P *= tld[o + j];
            Prow[tid] = P;
        }
        if (tid < NVAR) Spart[tid] = 0.0f;
        __syncthreads();

        // pass 2: c2v message + gated update + scatter
        for (int e = tid; e < E1; e += TPB) {
            unsigned pk = ev[e];
            int v  = (int)(pk & 0xFFFFu);
            int lr = (int)(pk >> 16);
            float tj = tld[e];
            float ts = (fabsf(tj) < 1e-7f) ? ((tj >= 0.0f) ? 1e-7f : -1e-7f) : tj;
            float r  = Prow[lr] * __builtin_amdgcn_rcpf(ts);
            r = fminf(1.0f - 1e-6f, fmaxf(-1.0f + 1e-6f, r));
            float Mn = __logf((1.0f + r) * __builtin_amdgcn_rcpf(1.0f - r)) * wld[e];
            float Mo = fmaf(gate, Mn, gbar * Mld[e]);
            Mld[e] = Mo;
            atomicAdd(&Spart[v], Mo);
        }
        __syncthreads();

        // publish partial S (agent-scope, bypasses stale-L2 hazards)
        const int par = t & 1;
        float*       myS = Sg + (((size_t)par * B_SZ + b) * 2 + grp) * NVAR;
        const float* otS = Sg + (((size_t)par * B_SZ + b) * 2 + (grp ^ 1)) * NVAR;
        if (tid < NVAR)
            __hip_atomic_store(&myS[tid], Spart[tid],
                               __ATOMIC_RELAXED, __HIP_MEMORY_SCOPE_AGENT);
        const bool wait = !(grp == 1 && t == NITER - 1);
        __syncthreads();   // drains the stores (vmcnt 0) for the whole block

        // two-level grid barrier: 8 leaf counters + 1 root, per iteration
        int* leafp = bar + (t * 9 + (bid >> 5)) * 16;
        int* rootp = bar + (t * 9 + 8) * 16;
        if (tid == 0) {
            __hip_atomic_fetch_add(leafp, 1, __ATOMIC_RELEASE, __HIP_MEMORY_SCOPE_AGENT);
            if ((bid & 31) == 0) {   // leaf leader (always a grp-0 block)
                while (__hip_atomic_load(leafp, __ATOMIC_ACQUIRE,
                                         __HIP_MEMORY_SCOPE_AGENT) < 32)
                    __builtin_amdgcn_s_sleep(1);
                __hip_atomic_fetch_add(rootp, 1, __ATOMIC_RELEASE, __HIP_MEMORY_SCOPE_AGENT);
            }
            if (wait)
                while (__hip_atomic_load(rootp, __ATOMIC_ACQUIRE,
                                         __HIP_MEMORY_SCOPE_AGENT) < 8)
                    __builtin_amdgcn_s_sleep(1);
        }
        if (!wait) return;           // grp-1 blocks exit after last arrival
        __syncthreads();

        // combine partials; prepare next iteration's xs; posterior (grp 0)
        float post = 0.0f, ap = 0.0f;
        const float ptn = (t < NITER - 1) ? ipl[t + 1] : 0.0f;
        if (tid < NVAR) {
            float rs = __hip_atomic_load(&otS[tid], __ATOMIC_RELAXED,
                                         __HIP_MEMORY_SCOPE_AGENT);
            float s2 = Spart[tid] + rs;
            xs[tid]  = fmaf(ptn, xln[tid], s2);
            post = fmaf(pt, xln[tid], s2);
            ap   = fabsf(post);
        }
        if (grp == 0) {
            #pragma unroll
            for (int o = 32; o; o >>= 1) ap += __shfl_down(ap, o, 64);
            if (lane == 0) red[wid] = ap;
            __syncthreads();
            if (tid == 0) {
                float s = 0.0f;
                #pragma unroll
                for (int i = 0; i < 16; ++i) s += red[i];
                scalS = (float)NVAR / s;
            }
            __syncthreads();
            if (tid < KINFO) pooled[tid] += ot * post * scalS;
        }
        __syncthreads();             // xs stable before next pass 1
    }

    // only grp-0 blocks reach here
    if (tid < KINFO) {
        float o = pooled[tid] * (1.0f / NITER) + skipp[0] * xln[tid];
        out[(size_t)b * KINFO + tid] = 1.0f / (1.0f + __expf(o));
    }
}

extern "C" void kernel_launch(void* const* d_in, const int* in_sizes, int n_in,
                              void* d_out, int out_size, void* d_ws, size_t ws_size,
                              hipStream_t stream) {
    const float* inp    = (const float*)d_in[0];
    const float* H      = (const float*)d_in[1];
    const float* sigma2 = (const float*)d_in[2];
    const float* ipond  = (const float*)d_in[3];
    const float* opond  = (const float*)d_in[4];
    const float* skipp  = (const float*)d_in[5];
    const float* wcv    = (const float*)d_in[6];
    const float* gatel  = (const float*)d_in[7];
    float* out = (float*)d_out;

    // ws layout: Sg [2][B][2][NVAR] f32, then barrier counters (45 slots x 64B)
    float* Sg = (float*)d_ws;
    int*   bar = (int*)((char*)d_ws + (size_t)2 * B_SZ * 2 * NVAR * sizeof(float));

    hipMemsetAsync(bar, 0, NITER * 9 * 16 * sizeof(int), stream);
    decode<<<2 * B_SZ, TPB, 0, stream>>>(inp, H, sigma2, ipond, opond, skipp,
                                         wcv, gatel, Sg, bar, out);
}

// Round 4
// 181.966 us; speedup vs baseline: 1.4004x; 1.4004x over previous
//
#include <hip/hip_runtime.h>

#define B_SZ  128
#define MCHK  288
#define NVAR  576
#define KINFO 288
#define NITER 5
#define ECAP  3712         // edges per batch element: mean 3318, sd ~57 (6.9 sigma)
#define TPB   1024

// ---------------------------------------------------------------------------
// One fused kernel, one block per batch element, no cross-block coupling.
// Phase 0: normalize LLRs; extract edges from this b's H slice (coalesced
//          float4 + ballot compaction), grabbing w_cv from the same columns
//          out of registers (w_cv rows are L2-resident: shared by all blocks).
// Loop (3 barriers/iter): edge-parallel tanh -> row-parallel 4-batched
//          product -> edge-parallel message + gated update + LDS scatter
//          into a fresh S snapshot (6 snapshots kept; normalization deferred).
// Phase 2: all 5 posterior normalizations + pooling + sigmoid, once.
// ---------------------------------------------------------------------------
__global__ __launch_bounds__(TPB) void decode(
    const float* __restrict__ inp,   const float* __restrict__ H,
    const float* __restrict__ sigma2,const float* __restrict__ ipond,
    const float* __restrict__ opond, const float* __restrict__ skipp,
    const float* __restrict__ wcv,   const float* __restrict__ gatel,
    float* __restrict__ out)
{
    __shared__ float Mld[ECAP];            // per-edge message
    __shared__ float tld[ECAP];            // per-edge tanh
    __shared__ float wld[ECAP];            // per-edge weight
    __shared__ unsigned int ev[ECAP];      // (row<<16)|var
    __shared__ float Sb[NITER + 1][NVAR];  // S after iteration t lives in Sb[t+1]
    __shared__ float xln[NVAR];            // normalized LLRs
    __shared__ float Prow[MCHK];
    __shared__ int   rcnt[MCHK], roff[MCHK];
    __shared__ float red[NITER * 16];
    __shared__ float scalv[NITER];
    __shared__ int   Ecnt;

    const int b    = blockIdx.x;
    const int tid  = threadIdx.x;
    const int wid  = tid >> 6;
    const int lane = tid & 63;

    const float sig  = sigma2[b];
    const float gate = 1.0f / (1.0f + __expf(-gatel[0]));
    const float gbar = 1.0f - gate;

    float ipl[NITER], opl[NITER];
    #pragma unroll
    for (int t = 0; t < NITER; ++t) { ipl[t] = ipond[t]; opl[t] = opond[t]; }

    // ---- Phase 0a: LLRs + mean|llr| ----
    float l = 0.0f, al = 0.0f, xv = 0.0f;
    if (tid < NVAR) { l = -4.0f * inp[(size_t)b * NVAR + tid] / sig; al = fabsf(l); }
    #pragma unroll
    for (int o = 32; o; o >>= 1) al += __shfl_down(al, o, 64);
    if (lane == 0) red[wid] = al;
    if (tid == 0) Ecnt = 0;
    for (int i = tid; i < (NITER + 1) * NVAR; i += TPB) ((float*)Sb)[i] = 0.0f;
    __syncthreads();
    if (wid == 0) {
        float s = (lane < 16) ? red[lane] : 0.0f;
        s += __shfl_down(s, 8, 64); s += __shfl_down(s, 4, 64);
        s += __shfl_down(s, 2, 64); s += __shfl_down(s, 1, 64);
        if (lane == 0) scalv[0] = (float)NVAR / s;
    }
    __syncthreads();
    if (tid < NVAR) { xv = l * scalv[0]; xln[tid] = xv; }

    // ---- Phase 0b: edge extraction (wave w -> rows w, w+16, ...) ----
    {
        const float* Hb = H + (size_t)b * MCHK * NVAR;
        const unsigned long long lt = (1ull << lane) - 1ull;
        for (int i = 0; i < MCHK / 16; ++i) {
            int r = wid + 16 * i;
            const float4* h4 = (const float4*)(Hb + (size_t)r * NVAR);
            const float4* w4 = (const float4*)(wcv + (size_t)r * NVAR);
            float4 a  = h4[lane];
            float4 b4 = h4[64 + lane];
            float  c  = ((const float*)h4)[512 + lane];
            float4 wa = w4[lane];
            float4 wb = w4[64 + lane];
            float  wc = ((const float*)w4)[512 + lane];
            unsigned long long mk[9];
            mk[0]=__ballot(a.x!=0.f);  mk[1]=__ballot(a.y!=0.f);
            mk[2]=__ballot(a.z!=0.f);  mk[3]=__ballot(a.w!=0.f);
            mk[4]=__ballot(b4.x!=0.f); mk[5]=__ballot(b4.y!=0.f);
            mk[6]=__ballot(b4.z!=0.f); mk[7]=__ballot(b4.w!=0.f);
            mk[8]=__ballot(c!=0.f);
            int tot = 0;
            #pragma unroll
            for (int k = 0; k < 9; ++k) tot += __popcll(mk[k]);
            int o0 = 0;
            if (lane == 0) o0 = atomicAdd(&Ecnt, tot);
            o0 = __shfl(o0, 0, 64);
            int cc = (o0 >= ECAP) ? 0 : ((o0 + tot > ECAP) ? (ECAP - o0) : tot);
            if (lane == 0) { roff[r] = o0; rcnt[r] = cc; }
            float wv[9] = {wa.x, wa.y, wa.z, wa.w, wb.x, wb.y, wb.z, wb.w, wc};
            int base = 0;
            #pragma unroll
            for (int k = 0; k < 9; ++k) {
                bool nz = (mk[k] >> lane) & 1ull;
                int col = (k < 4) ? (4 * lane + k)
                        : (k < 8) ? (256 + 4 * lane + (k - 4))
                                  : (512 + lane);
                if (nz) {
                    int p = base + __popcll(mk[k] & lt);
                    if (p < cc) {
                        int e = o0 + p;
                        ev[e]  = ((unsigned)r << 16) | (unsigned)col;
                        wld[e] = wv[k];
                        Mld[e] = 0.0f;
                    }
                }
                base += __popcll(mk[k]);
            }
        }
    }
    __syncthreads();
    const int E = (Ecnt > ECAP) ? ECAP : Ecnt;

    // ---- BP iterations: 3 barriers each, no reductions inside ----
    for (int t = 0; t < NITER; ++t) {
        const float pt = ipl[t];
        const float* St = Sb[t];
        float*       Sn = Sb[t + 1];

        // P1: per-edge tanh(0.5*clip(pt*xln[v] + S[v] - M[e]))
        for (int e = tid; e < E; e += TPB) {
            int v   = (int)(ev[e] & 0xFFFFu);
            float V = fmaf(pt, xln[v], St[v]) - Mld[e];
            V = fminf(15.0f, fmaxf(-15.0f, V));
            float ex = __expf(V);
            float te = (ex - 1.0f) * __builtin_amdgcn_rcpf(ex + 1.0f);
            float x  = 0.5f * V, x2 = x * x;
            float tp = x * fmaf(x2, fmaf(x2, fmaf(x2, -0.05396825f, 0.13333333f),
                                         -0.33333333f), 1.0f);
            tld[e] = (fabsf(V) < 0.5f) ? tp : te;
        }
        __syncthreads();

        // P2: row products, 4 independent partials (batches the LDS latency)
        if (tid < MCHK) {
            int o = roff[tid], oe = o + rcnt[tid];
            float p0 = 1.0f, p1 = 1.0f, p2 = 1.0f, p3 = 1.0f;
            int j = o;
            for (; j + 4 <= oe; j += 4) {
                float t0 = tld[j], t1 = tld[j + 1], t2 = tld[j + 2], t3 = tld[j + 3];
                p0 *= t0; p1 *= t1; p2 *= t2; p3 *= t3;
            }
            for (; j < oe; ++j) p0 *= tld[j];
            Prow[tid] = (p0 * p1) * (p2 * p3);
        }
        __syncthreads();

        // P3: per-edge c2v message + gated update + scatter into Sn
        for (int e = tid; e < E; e += TPB) {
            unsigned pk = ev[e];
            int v = (int)(pk & 0xFFFFu);
            int r = (int)(pk >> 16);
            float tj = tld[e];
            float ts = (fabsf(tj) < 1e-7f) ? ((tj >= 0.0f) ? 1e-7f : -1e-7f) : tj;
            float rr = Prow[r] * __builtin_amdgcn_rcpf(ts);
            rr = fminf(1.0f - 1e-6f, fmaxf(-1.0f + 1e-6f, rr));
            float Mn = __logf((1.0f + rr) * __builtin_amdgcn_rcpf(1.0f - rr)) * wld[e];
            float Mo = fmaf(gate, Mn, gbar * Mld[e]);
            Mld[e] = Mo;
            atomicAdd(&Sn[v], Mo);
        }
        __syncthreads();
    }

    // ---- Phase 2: all 5 normalizations at once, pooling, output ----
    float ap[NITER] = {0, 0, 0, 0, 0};
    if (tid < NVAR) {
        #pragma unroll
        for (int t = 0; t < NITER; ++t)
            ap[t] = fabsf(fmaf(ipl[t], xv, Sb[t + 1][tid]));
    }
    #pragma unroll
    for (int o = 32; o; o >>= 1) {
        #pragma unroll
        for (int t = 0; t < NITER; ++t) ap[t] += __shfl_down(ap[t], o, 64);
    }
    if (lane == 0) {
        #pragma unroll
        for (int t = 0; t < NITER; ++t) red[t * 16 + wid] = ap[t];
    }
    __syncthreads();
    if (wid == 0) {
        #pragma unroll
        for (int t = 0; t < NITER; ++t) {
            float s = (lane < 16) ? red[t * 16 + lane] : 0.0f;
            s += __shfl_down(s, 8, 64); s += __shfl_down(s, 4, 64);
            s += __shfl_down(s, 2, 64); s += __shfl_down(s, 1, 64);
            if (lane == 0) scalv[t] = (float)NVAR / s;
        }
    }
    __syncthreads();
    if (tid < KINFO) {
        float acc = 0.0f;
        #pragma unroll
        for (int t = 0; t < NITER; ++t)
            acc += opl[t] * fmaf(ipl[t], xv, Sb[t + 1][tid]) * scalv[t];
        float o = acc * (1.0f / NITER) + skipp[0] * xv;
        out[(size_t)b * KINFO + tid] = 1.0f / (1.0f + __expf(o));
    }
}

extern "C" void kernel_launch(void* const* d_in, const int* in_sizes, int n_in,
                              void* d_out, int out_size, void* d_ws, size_t ws_size,
                              hipStream_t stream) {
    const float* inp    = (const float*)d_in[0];
    const float* H      = (const float*)d_in[1];
    const float* sigma2 = (const float*)d_in[2];
    const float* ipond  = (const float*)d_in[3];
    const float* opond  = (const float*)d_in[4];
    const float* skipp  = (const float*)d_in[5];
    const float* wcv    = (const float*)d_in[6];
    const float* gatel  = (const float*)d_in[7];
    float* out = (float*)d_out;

    decode<<<B_SZ, TPB, 0, stream>>>(inp, H, sigma2, ipond, opond, skipp,
                                     wcv, gatel, out);
}